// Round 11
// baseline (2693.026 us; speedup 1.0000x reference)
//
#include <hip/hip_runtime.h>

typedef unsigned short u16;

#define NWG 256
#define NT  256
#define TS  512
#define HD  1024
#define BS  128
#define NI  64
#define NO  64
#define XR  16      // batch rows per XCD
#define CC  32      // hidden cols per CU
#define RCP 17      // redC padded row stride

typedef __attribute__((ext_vector_type(8))) short bf16x8;
typedef __attribute__((ext_vector_type(4))) float f32x4;

__device__ __forceinline__ float bf2f(u16 u) {
    union { unsigned int i; float f; } v; v.i = ((unsigned int)u) << 16; return v.f;
}
__device__ __forceinline__ u16 f2bf(float f) {
    union { float fl; unsigned int i; } v; v.fl = f;
    unsigned int x = v.i;
    return (u16)((x + 0x7fffu + ((x >> 16) & 1u)) >> 16);  // RNE, finite inputs
}
__device__ __forceinline__ float ldv(const void* p, size_t i, bool isf32) {
    return isf32 ? ((const float*)p)[i] : bf2f(((const u16*)p)[i]);
}

// L2-executed atomic returning old value (sc0 = return-old). Round-6 finding:
// atomic RMW is the ONLY read path that promptly observes peer-CU stores.
__device__ __forceinline__ unsigned l2_atomic_add(unsigned* p, unsigned v) {
    unsigned old;
    asm volatile("global_atomic_add %0, %1, %2, off sc0\n\t"
                 "s_waitcnt vmcnt(0)"
                 : "=&v"(old) : "v"(p), "v"(v) : "memory");
    return old;
}
// Fire-and-forget plain store (sc0, write-through L2, no wait). Round-10
// lesson: RMW publishes serialize at the target line; a plain store doesn't.
// Round-6 validated plain-store publish + atomic-RMW poll visibility.
__device__ __forceinline__ void l2_store_nr(unsigned* p, unsigned v) {
    asm volatile("global_store_dword %0, %1, off sc0" :: "v"(p), "v"(v) : "memory");
}

// 8 A-fragments (one K-quarter) via sc0 loads (L1 bypass -> XCD L2, where peer
// CUs' write-through stores live). Proven correct for data in rounds 4/6/7/9/10.
__device__ __forceinline__ void load_a_frags(const u16* ap, bf16x8* a) {
    asm volatile(
        "global_load_dwordx4 %0, %8, off sc0\n\t"
        "global_load_dwordx4 %1, %8, off offset:64 sc0\n\t"
        "global_load_dwordx4 %2, %8, off offset:128 sc0\n\t"
        "global_load_dwordx4 %3, %8, off offset:192 sc0\n\t"
        "global_load_dwordx4 %4, %8, off offset:256 sc0\n\t"
        "global_load_dwordx4 %5, %8, off offset:320 sc0\n\t"
        "global_load_dwordx4 %6, %8, off offset:384 sc0\n\t"
        "global_load_dwordx4 %7, %8, off offset:448 sc0\n\t"
        "s_waitcnt vmcnt(0)"
        : "=&v"(a[0]), "=&v"(a[1]), "=&v"(a[2]), "=&v"(a[3]),
          "=&v"(a[4]), "=&v"(a[5]), "=&v"(a[6]), "=&v"(a[7])
        : "v"(ap) : "memory");
}

// Per-PRODUCER flag, 64B stride. flag[slot] = v <=> CU `slot` published h_{v-1}
// (and retired its reads of h_{v-2}). Publish = ONE plain store to own line
// (no RMW funnel); poll = wave-parallel atomic reads of 32 DISTINCT lines.
#define FL_STRIDE 16    // u32s = 64B

// LDS ~156KB -> exactly 1 WG/CU (required by the per-XCD ticket scheme).
__global__ __launch_bounds__(NT)
void arnn_xcd(const void* __restrict__ xv,
              const void* __restrict__ encwv,
              const void* __restrict__ encbv,
              const void* __restrict__ recwv,
              const void* __restrict__ fgtwv,
              const void* __restrict__ decwv,
              const void* __restrict__ decbv,
              const void* __restrict__ hinitwv,
              const void* __restrict__ hinitbv,
              void* __restrict__ outv,
              u16* __restrict__ h0buf,
              u16* __restrict__ h1buf,
              unsigned* __restrict__ tickets,
              unsigned* __restrict__ flags)
{
    // WB: 4 n-tiles of 16 cols in MFMA B-frag lane order.
    // tile0: rec cols j0..j0+15, 34 k-steps (32 rec K=1024 + 2 enc K=64)
    // tile1: rec cols j0+16..j0+31, 34 k-steps
    // tile2/3: fgt cols, 32 k-steps. Entry: WB[(tb+ks)*64 + lane][8].
    __shared__ short WB[132 * 64 * 8];          // 135168 B
    __shared__ float redC[4 * 5 * 16 * RCP];    // 21760 B: [kq][tile(4=dec)][row][col]
    __shared__ float hst[XR * CC];              // fp32 master hidden slice
    __shared__ float encbS[CC];
    __shared__ float decbLS[16];
    __shared__ unsigned s_xcd, s_slot;
    __shared__ int s_f32;

    const int tid  = threadIdx.x;
    const int wave = tid >> 6;
    const int lane = tid & 63;
    const int m    = lane & 15;      // C row / A row (batch-local)
    const int quad = lane >> 4;      // k-subblock within K=32

    // ---- identify XCD, claim per-XCD CU slot ----
    if (tid == 0) {
        unsigned xcc;
        asm volatile("s_getreg_b32 %0, hwreg(HW_REG_XCC_ID, 0, 4)" : "=s"(xcc));
        xcc &= 7u;
        unsigned slot = l2_atomic_add(tickets + xcc * 16, 1u);
        s_xcd = xcc;
        s_slot = slot & 31u;
        s_f32 = 0;
    }
    __syncthreads();
    { // runtime dtype detection on rec_w raw bits (round-1 post-mortem)
        float v = bf2f(((const u16*)recwv)[tid]);
        if (!(v >= -1.0f && v <= 1.0f)) s_f32 = 1;
    }
    __syncthreads();
    const bool isf32 = (s_f32 != 0);
    const int xcd  = (int)s_xcd;
    const int slot = (int)s_slot;
    const int b0   = xcd * XR;       // this XCD's batch rows
    const int j0   = slot * CC;      // this CU's hidden cols
    const int dt   = slot & 3;       // dec tile: out cols 16dt..16dt+15
    unsigned* flX   = flags + (size_t)xcd * 32 * FL_STRIDE;   // XCD's 32 flags
    unsigned* flOwn = flX + slot * FL_STRIDE;                 // this CU's flag

    // ---- stage weights into LDS in B-frag order ----
    for (int idx = tid; idx < 132 * 64; idx += NT) {
        int ksg = idx >> 6, l = idx & 63, n = l & 15, q = l >> 4;
        int tile, ksl;
        if (ksg < 34)       { tile = 0; ksl = ksg; }
        else if (ksg < 68)  { tile = 1; ksl = ksg - 34; }
        else if (ksg < 100) { tile = 2; ksl = ksg - 68; }
        else                { tile = 3; ksl = ksg - 100; }
        int j = j0 + ((tile & 1) << 4) + n;
        bf16x8 v;
        if (!isf32) {
            const u16* src;
            if (tile < 2) src = (ksl < 32) ? (const u16*)recwv + (size_t)j * HD + ksl * 32 + q * 8
                                           : (const u16*)encwv + (size_t)j * NI + (ksl - 32) * 32 + q * 8;
            else          src = (const u16*)fgtwv + (size_t)j * HD + ksl * 32 + q * 8;
            v = *(const bf16x8*)src;
        } else {
            const float* src;
            if (tile < 2) src = (ksl < 32) ? (const float*)recwv + (size_t)j * HD + ksl * 32 + q * 8
                                           : (const float*)encwv + (size_t)j * NI + (ksl - 32) * 32 + q * 8;
            else          src = (const float*)fgtwv + (size_t)j * HD + ksl * 32 + q * 8;
            #pragma unroll
            for (int i = 0; i < 8; ++i) v[i] = (short)f2bf(src[i]);
        }
        *(bf16x8*)&WB[idx * 8] = v;
    }
    __syncthreads();     // WB fully staged before register pull

    // ---- register-resident fragments (round-8 lesson: stay <=256 regs) ----
    bf16x8 Breg[2][8];   // rec tiles 0,1 for this wave's K-quarter: 64 regs
    #pragma unroll
    for (int ks = 0; ks < 8; ++ks) {
        int kb = wave * 8 + ks;
        Breg[0][ks] = *(const bf16x8*)&WB[((0  + kb) * 64 + lane) * 8];
        Breg[1][ks] = *(const bf16x8*)&WB[((34 + kb) * 64 + lane) * 8];
    }
    bf16x8 Ereg[2];      // enc-tail B-frags (waves 0,1 only): 8 regs
    if (wave < 2) {
        Ereg[0] = *(const bf16x8*)&WB[((32 + wave) * 64 + lane) * 8];
        Ereg[1] = *(const bf16x8*)&WB[((34 + 32 + wave) * 64 + lane) * 8];
    }
    bf16x8 dfr[8];       // dec B-frags for this wave's K-quarter: 32 regs
    {
        int o = 16 * dt + m;         // out column
        #pragma unroll
        for (int ks = 0; ks < 8; ++ks) {
            int kb = wave * 256 + ks * 32 + quad * 8;
            if (!isf32) dfr[ks] = *(const bf16x8*)((const u16*)decwv + (size_t)o * HD + kb);
            else {
                const float* src = (const float*)decwv + (size_t)o * HD + kb;
                #pragma unroll
                for (int i = 0; i < 8; ++i) dfr[ks][i] = (short)f2bf(src[i]);
            }
        }
    }
    if (tid < CC) encbS[tid] = ldv(encbv, j0 + tid, isf32);
    if (tid < 16) decbLS[tid] = ldv(decbv, 16 * dt + tid, isf32);
    // h0 = hinit_w[:,0] + hinit_b (same for all batch rows)
    for (int e = tid; e < XR * CC; e += NT) {
        int r = e >> 5, c = e & 31;
        float v = ldv(hinitwv, j0 + c, isf32) + ldv(hinitbv, j0 + c, isf32);
        hst[e] = v;
        h0buf[(size_t)(b0 + r) * HD + j0 + c] = f2bf(v);
    }
    __syncthreads();                             // h0 stores acked by L2 (vmcnt(0))
    if (tid == 0) l2_store_nr(flOwn, 1u);        // publish h_0 (plain store, own line)

    // ---- recurrence ----
    // all flags >= t+1 <=> all 32 CUs of this XCD published h_t and retired
    // their h_{t-1}-buffer reads: ping-pong overwrite at step t is WAR-safe.
    for (int t = 0; t < TS; ++t) {
        f32x4 acc[5];
        #pragma unroll
        for (int tt = 0; tt < 5; ++tt) acc[tt] = (f32x4){0.f, 0.f, 0.f, 0.f};

        // enc contribution BEFORE the wait (x is read-only input)
        if (wave < 2) {
            bf16x8 xf;
            size_t xb = (size_t)(b0 + m) * (TS * NI) + (size_t)t * NI + wave * 32 + quad * 8;
            if (!isf32) xf = *(const bf16x8*)((const u16*)xv + xb);
            else {
                const float* xp = (const float*)xv + xb;
                #pragma unroll
                for (int i = 0; i < 8; ++i) xf[i] = (short)f2bf(xp[i]);
            }
            acc[0] = __builtin_amdgcn_mfma_f32_16x16x32_bf16(xf, Ereg[0], acc[0], 0, 0, 0);
            acc[1] = __builtin_amdgcn_mfma_f32_16x16x32_bf16(xf, Ereg[1], acc[1], 0, 0, 0);
        }

        // Wave-0 poll: 64 lanes cover 32 distinct flag lines (2 lanes each) --
        // parallel RMWs across banks, ~1 RTT/round, no shared-line funnel.
        if (wave == 0) {
            unsigned* p = flX + (lane & 31) * FL_STRIDE;
            unsigned target = (unsigned)(t + 1);
            for (;;) {
                unsigned f = l2_atomic_add(p, 0u);
                if (__all((int)(f >= target))) break;
            }
        }
        __syncthreads();               // release waves 1-3

        const u16* cur = (t & 1) ? h1buf : h0buf;
        u16*       nxt = (t & 1) ? h0buf : h1buf;

        bf16x8 a[8];
        load_a_frags(cur + (size_t)(b0 + m) * HD + wave * 256 + quad * 8, a);

        #pragma unroll
        for (int ks = 0; ks < 8; ++ks) {
            int kb = wave * 8 + ks;
            bf16x8 bf2 = *(const bf16x8*)&WB[((68  + kb) * 64 + lane) * 8];
            bf16x8 bf3 = *(const bf16x8*)&WB[((100 + kb) * 64 + lane) * 8];
            acc[0] = __builtin_amdgcn_mfma_f32_16x16x32_bf16(a[ks], Breg[0][ks], acc[0], 0, 0, 0);
            acc[1] = __builtin_amdgcn_mfma_f32_16x16x32_bf16(a[ks], Breg[1][ks], acc[1], 0, 0, 0);
            acc[2] = __builtin_amdgcn_mfma_f32_16x16x32_bf16(a[ks], bf2,         acc[2], 0, 0, 0);
            acc[3] = __builtin_amdgcn_mfma_f32_16x16x32_bf16(a[ks], bf3,         acc[3], 0, 0, 0);
            acc[4] = __builtin_amdgcn_mfma_f32_16x16x32_bf16(a[ks], dfr[ks],     acc[4], 0, 0, 0);
        }

        // C-layout 16x16: col = lane&15, row = quad*4 + reg
        #pragma unroll
        for (int tt = 0; tt < 5; ++tt) {
            #pragma unroll
            for (int r = 0; r < 4; ++r)
                redC[((wave * 5 + tt) * 16 + quad * 4 + r) * RCP + m] = acc[tt][r];
        }
        __syncthreads();

        // decode h_t -> out[t-1]
        if (slot < 4 && t > 0) {
            int r = tid >> 4, col = tid & 15;
            float o = decbLS[col];
            #pragma unroll
            for (int kq = 0; kq < 4; ++kq)
                o += redC[((kq * 5 + 4) * 16 + r) * RCP + col];
            size_t oi = (size_t)(t - 1) * (BS * NO) + (size_t)(b0 + r) * NO + 16 * dt + col;
            if (isf32) ((float*)outv)[oi] = o; else ((u16*)outv)[oi] = f2bf(o);
        }
        // cross-wave K-reduction + elementwise update; 2 adjacent cols/thread,
        // h written as ONE packed dword (halves the stores the barrier drains)
        {
            int e = tid * 2;
            int r = e >> 5, c = e & 31, tl = c >> 4, col = c & 15;
            float pr0 = encbS[c],     pf0 = 0.f;
            float pr1 = encbS[c + 1], pf1 = 0.f;
            #pragma unroll
            for (int kq = 0; kq < 4; ++kq) {
                pr0 += redC[((kq * 5 + tl) * 16 + r) * RCP + col];
                pr1 += redC[((kq * 5 + tl) * 16 + r) * RCP + col + 1];
                pf0 += redC[((kq * 5 + 2 + tl) * 16 + r) * RCP + col];
                pf1 += redC[((kq * 5 + 2 + tl) * 16 + r) * RCP + col + 1];
            }
            float fg0 = 1.0f / (1.0f + __expf(-pf0));
            float fg1 = 1.0f / (1.0f + __expf(-pf1));
            float hn0 = pr0 / (1.0f + fabsf(pr0));
            float hn1 = pr1 / (1.0f + fabsf(pr1));
            float h0v = hst[e], h1v = hst[e + 1];
            float hv0 = h0v + fg0 * (hn0 - h0v);
            float hv1 = h1v + fg1 * (hn1 - h1v);
            hst[e] = hv0; hst[e + 1] = hv1;
            unsigned pk = (unsigned)f2bf(hv0) | ((unsigned)f2bf(hv1) << 16);
            *(unsigned*)(nxt + (size_t)(b0 + r) * HD + j0 + c) = pk;
        }
        __syncthreads();                         // all waves' h/out stores acked by L2
        if (tid == 0) l2_store_nr(flOwn, (unsigned)(t + 2));   // publish h_{t+1}
    }

    // ---- epilogue: out[511] = decode(h_512); final hidden ----
    if (wave == 0) {
        unsigned* p = flX + (lane & 31) * FL_STRIDE;
        unsigned target = (unsigned)(TS + 1);
        for (;;) {
            unsigned f = l2_atomic_add(p, 0u);
            if (__all((int)(f >= target))) break;
        }
    }
    __syncthreads();
    {
        bf16x8 a[8];
        load_a_frags(h0buf + (size_t)(b0 + m) * HD + wave * 256 + quad * 8, a);
        f32x4 ac = (f32x4){0.f, 0.f, 0.f, 0.f};
        #pragma unroll
        for (int ks = 0; ks < 8; ++ks)
            ac = __builtin_amdgcn_mfma_f32_16x16x32_bf16(a[ks], dfr[ks], ac, 0, 0, 0);
        #pragma unroll
        for (int r = 0; r < 4; ++r)
            redC[((wave * 5 + 4) * 16 + quad * 4 + r) * RCP + m] = ac[r];
        __syncthreads();
        if (slot < 4) {
            int r = tid >> 4, col = tid & 15;
            float o = decbLS[col];
            #pragma unroll
            for (int kq = 0; kq < 4; ++kq)
                o += redC[((kq * 5 + 4) * 16 + r) * RCP + col];
            size_t oi = (size_t)511 * (BS * NO) + (size_t)(b0 + r) * NO + 16 * dt + col;
            if (isf32) ((float*)outv)[oi] = o; else ((u16*)outv)[oi] = f2bf(o);
        }
        for (int e = tid; e < XR * CC; e += NT) {
            int r = e >> 5, c = e & 31;
            size_t oi = (size_t)TS * BS * NO + (size_t)(b0 + r) * HD + j0 + c;
            float v = hst[e];
            if (isf32) ((float*)outv)[oi] = v; else ((u16*)outv)[oi] = f2bf(v);
        }
    }
}

extern "C" void kernel_launch(void* const* d_in, const int* in_sizes, int n_in,
                              void* d_out, int out_size, void* d_ws, size_t ws_size,
                              hipStream_t stream) {
    (void)in_sizes; (void)n_in; (void)out_size; (void)ws_size;
    const void* xv       = d_in[0];
    const void* encwv    = d_in[1];
    const void* encbv    = d_in[2];
    const void* recwv    = d_in[3];
    const void* fgtwv    = d_in[4];
    const void* decwv    = d_in[5];
    const void* decbv    = d_in[6];
    const void* hinitwv  = d_in[7];
    const void* hinitbv  = d_in[8];
    void* outv = d_out;

    unsigned* tickets = (unsigned*)d_ws;                       // 8 x 64B-stride
    unsigned* flags   = (unsigned*)((char*)d_ws + 4096);       // 8 XCDs x 32 CUs x 64B
    u16* h0buf = (u16*)((char*)d_ws + 524288);
    u16* h1buf = h0buf + (size_t)BS * HD;

    // zero tickets + flags each launch (ws is re-poisoned to 0xAA)
    hipMemsetAsync(d_ws, 0, 4096 + 8 * 32 * 64, stream);

    void* args[] = { (void*)&xv, (void*)&encwv, (void*)&encbv, (void*)&recwv,
                     (void*)&fgtwv, (void*)&decwv, (void*)&decbv,
                     (void*)&hinitwv, (void*)&hinitbv,
                     (void*)&outv, (void*)&h0buf, (void*)&h1buf,
                     (void*)&tickets, (void*)&flags };
    // Round-8 lesson: NEVER ignore the cooperative-launch return code.
    hipError_t err = hipLaunchCooperativeKernel((void*)arnn_xcd, dim3(NWG), dim3(NT), args, 0, stream);
    if (err != hipSuccess) {
        hipLaunchKernelGGL(arnn_xcd, dim3(NWG), dim3(NT), 0, stream,
                           xv, encwv, encbv, recwv, fgtwv, decwv, decbv,
                           hinitwv, hinitbv, outv, h0buf, h1buf, tickets, flags);
    }
}